// Round 11
// baseline (249.953 us; speedup 1.0000x reference)
//
#include <hip/hip_runtime.h>
#include <hip/hip_bf16.h>
#include <math.h>

typedef unsigned long long u64;
typedef unsigned short ushort_t;
typedef float f32x4 __attribute__((ext_vector_type(4)));
typedef short s16x8 __attribute__((ext_vector_type(8)));

#define NN 4096
#define NF 1024
#define NH 512
#define NC 32
#define LDP 40

__device__ inline float bf2f(ushort_t u) {
    unsigned int v = ((unsigned int)u) << 16;
    return __uint_as_float(v);
}
__device__ inline ushort_t f2bf(float f) {
    __hip_bfloat16 h = __float2bfloat16(f);
    return *(ushort_t*)&h;
}

// ================= role: build one adj row (wave-wide), ELL padded to 8 =================
__device__ void role_build(int i, int l, const float* __restrict__ adj,
                           u64* __restrict__ B1, int* __restrict__ rowcnt,
                           int* __restrict__ rowcnt_true,
                           int* __restrict__ colidx, float* __restrict__ vals) {
    const float* row = adj + (size_t)i * NN + l * 64;
    const float4* row4 = (const float4*)row;
    u64 w = 0;
    #pragma unroll
    for (int k = 0; k < 16; ++k) {
        float4 v = row4[k];
        if (v.x > 0.f) w |= 1ULL << (4*k + 0);
        if (v.y > 0.f) w |= 1ULL << (4*k + 1);
        if (v.z > 0.f) w |= 1ULL << (4*k + 2);
        if (v.w > 0.f) w |= 1ULL << (4*k + 3);
    }
    B1[(size_t)i*64 + l] = w;
    int cnt = __popcll(w);
    int pre = cnt;
    #pragma unroll
    for (int o = 1; o < 64; o <<= 1) {
        int u = __shfl_up(pre, o, 64);
        if (l >= o) pre += u;
    }
    int excl = pre - cnt;
    int total = __shfl(pre, 63, 64);
    u64 ww = w;
    int idx = excl;
    while (ww) {
        int b = __ffsll((unsigned long long)ww) - 1;
        ww &= ww - 1;
        if (idx < 64) {
            colidx[i*64 + idx] = l*64 + b;
            vals[i*64 + idx] = row[b];
        }
        ++idx;
    }
    int tot = total < 64 ? total : 64;
    for (int s = tot + l; s < 64; s += 64) {
        colidx[i*64 + s] = 0;
        vals[i*64 + s] = 0.f;
    }
    if (l == 0) {
        rowcnt_true[i] = tot;
        int r8 = (tot + 7) & ~7;
        rowcnt[i] = r8 < 64 ? r8 : 64;
    }
}

// ================= role: W-transpose tile 32x32, fp32 [K][NH] -> bf16 [NH][Kd] =========
__device__ void role_wt(const float* __restrict__ W, ushort_t* __restrict__ Wt,
                        int ksrc0, int Kd, int idx, char* smem, int t) {
    float (*tile)[33] = (float(*)[33])smem;
    int ktiles = Kd >> 5;
    int kb = (idx % ktiles) * 32, nb = (idx / ktiles) * 32;
    int tc = t & 31, tr8 = t >> 5;
    for (int r = tr8; r < 32; r += 8)
        tile[r][tc] = W[(size_t)(ksrc0 + kb + r) * NH + nb + tc];
    __syncthreads();
    for (int r = tr8; r < 32; r += 8)
        Wt[(size_t)(nb + r) * Kd + kb + tc] = f2bf(tile[tc][r]);
}

// ================= role: boolean product row =================
__device__ void role_bsq(int i, int t, char* smem, const u64* __restrict__ Bidx,
                         const u64* __restrict__ Bdat, u64* __restrict__ Bout) {
    u64* ridx = (u64*)smem;
    u64* part = ridx + 64;
    int wid = t >> 6, lane = t & 63;
    if (t < 64) ridx[t] = Bidx[(size_t)i*64 + t];
    __syncthreads();
    u64 acc = 0;
    for (int u = wid*16; u < wid*16 + 16; ++u) {
        u64 w = ridx[u];
        while (w) {
            int k = u*64 + (__ffsll((unsigned long long)w) - 1);
            w &= (w - 1);
            acc |= Bdat[(size_t)k*64 + lane];
        }
    }
    part[wid*64 + lane] = acc;
    __syncthreads();
    if (t < 64) Bout[(size_t)i*64 + t] = part[t] | part[64+t] | part[128+t] | part[192+t];
}

// ================= role: bit transpose, one 64x64 tile per wave =================
__device__ void role_btrans(int tb, int wid, int l, char* smem,
                            const u64* __restrict__ B, u64* __restrict__ BT) {
    u64* ld = ((u64*)smem) + wid*64;
    int I = tb >> 6, J = tb & 63;
    ld[l] = B[(size_t)(I*64 + l)*64 + J];
    __syncthreads();
    u64 out = 0;
    #pragma unroll
    for (int r = 0; r < 64; ++r) out |= ((ld[r] >> l) & 1ULL) << r;
    BT[(size_t)(J*64 + l)*64 + I] = out;
}

// ================= role: ymat -> yc [NN][96] bf16 (8 rows/block) =================
__device__ void role_ymat(int rb, int t, char* smem, const u64* __restrict__ B,
                          const u64* __restrict__ BT, const u64* __restrict__ LC,
                          const float* __restrict__ asp, ushort_t* __restrict__ yc) {
    u64* LCt   = (u64*)smem;
    u64* rows  = LCt + 64*32;
    u64* rowsT = rows + 8*64;
    for (int k = t; k < 2048; k += 256) {
        int c = k >> 6, w = k & 63;
        LCt[w*32 + c] = LC[k];
    }
    for (int k = t; k < 512; k += 256) {
        int r = k >> 6, w = k & 63;
        rows[r*64 + w]  = B[(size_t)(rb + r)*64 + w];
        rowsT[r*64 + w] = BT[(size_t)(rb + r)*64 + w];
    }
    __syncthreads();
    int wid = t >> 6, lane = t & 63;
    int h = lane >> 5, c = lane & 31;
    int r = wid * 2 + h;
    int co = 0, ci = 0;
    #pragma unroll
    for (int w = 0; w < 64; ++w) {
        u64 lc = LCt[w*32 + c];
        co += __popcll(rows[r*64 + w]  & lc);
        ci += __popcll(rowsT[r*64 + w] & lc);
    }
    float a1 = asp[1], a2 = asp[2], a3 = asp[3];
    size_t i = rb + r;
    yc[i*96 + c]      = f2bf(a1 * (float)co);
    yc[i*96 + 32 + c] = f2bf(a2 * (float)ci);
    yc[i*96 + 64 + c] = f2bf(a3 * (float)(co + ci));
}

// ================= role: MFMA GEMM 64x64 tile, N=512, flexible A/C formats =========
__device__ void role_gemm(int bx, int tid, char* smem, const ushort_t* __restrict__ Abf,
                          const float* __restrict__ Af, int Ka,
                          const ushort_t* __restrict__ Bt, int K,
                          ushort_t* __restrict__ Cb, float* __restrict__ Cf) {
    ushort_t* As = (ushort_t*)smem;
    ushort_t* Bs = As + 64*LDP;
    int xcd = bx & 7, rest = bx >> 3;
    int nt = rest & 7, mt = (rest >> 3) * 8 + xcd;
    int bm = mt * 64, bn = nt * 64;
    int srow = tid >> 2, scol = (tid & 3) * 8;
    int wid = tid >> 6, lane = tid & 63;
    int fr = lane & 15, hi2 = lane >> 4, fk = hi2 * 8;
    f32x4 acc[4] = {{0,0,0,0},{0,0,0,0},{0,0,0,0},{0,0,0,0}};
    for (int k0 = 0; k0 < K; k0 += 32) {
        if (Abf) {
            *(s16x8*)&As[srow * LDP + scol] =
                *(const s16x8*)&Abf[(size_t)(bm + srow) * Ka + k0 + scol];
        } else {
            const float* ap = &Af[(size_t)(bm + srow) * Ka + k0 + scol];
            float4 a0 = *(const float4*)ap;
            float4 a1 = *(const float4*)(ap + 4);
            s16x8 o;
            o[0] = (short)f2bf(a0.x); o[1] = (short)f2bf(a0.y);
            o[2] = (short)f2bf(a0.z); o[3] = (short)f2bf(a0.w);
            o[4] = (short)f2bf(a1.x); o[5] = (short)f2bf(a1.y);
            o[6] = (short)f2bf(a1.z); o[7] = (short)f2bf(a1.w);
            *(s16x8*)&As[srow * LDP + scol] = o;
        }
        *(s16x8*)&Bs[srow * LDP + scol] =
            *(const s16x8*)&Bt[(size_t)(bn + srow) * K + k0 + scol];
        __syncthreads();
        s16x8 af = *(const s16x8*)&As[(wid * 16 + fr) * LDP + fk];
        #pragma unroll
        for (int j = 0; j < 4; ++j) {
            s16x8 bfv = *(const s16x8*)&Bs[(j * 16 + fr) * LDP + fk];
            acc[j] = __builtin_amdgcn_mfma_f32_16x16x32_bf16(af, bfv, acc[j], 0, 0, 0);
        }
        __syncthreads();
    }
    int drow = bm + wid * 16 + hi2 * 4;
    #pragma unroll
    for (int j = 0; j < 4; ++j) {
        int col = bn + j * 16 + fr;
        #pragma unroll
        for (int r = 0; r < 4; ++r) {
            if (Cb) Cb[(size_t)(drow + r) * NH + col] = f2bf(acc[j][r]);
            else    Cf[(size_t)(drow + r) * NH + col] = acc[j][r];
        }
    }
}

// ================= role: single-hop spmmF: + alpha, yv, bias; normalize; write feats ===
__device__ void role_spmmF(int i, int lane, const int* __restrict__ rc,
                           const int* __restrict__ ci, const float* __restrict__ vl,
                           const ushort_t* __restrict__ X, const float* __restrict__ yv,
                           const float* __restrict__ bias, int ln, float alpha,
                           ushort_t* __restrict__ F) {
    int cnt = rc[i];
    float acc[8] = {0,0,0,0,0,0,0,0};
    for (int p = 0; p < cnt; p += 8) {
        int4   c0 = *(const int4*)&ci[i*64 + p];
        int4   c1 = *(const int4*)&ci[i*64 + p + 4];
        float4 v0 = *(const float4*)&vl[i*64 + p];
        float4 v1 = *(const float4*)&vl[i*64 + p + 4];
        s16x8 x0 = *(const s16x8*)&X[(size_t)c0.x * NH + 8*lane];
        s16x8 x1 = *(const s16x8*)&X[(size_t)c0.y * NH + 8*lane];
        s16x8 x2 = *(const s16x8*)&X[(size_t)c0.z * NH + 8*lane];
        s16x8 x3 = *(const s16x8*)&X[(size_t)c0.w * NH + 8*lane];
        s16x8 x4 = *(const s16x8*)&X[(size_t)c1.x * NH + 8*lane];
        s16x8 x5 = *(const s16x8*)&X[(size_t)c1.y * NH + 8*lane];
        s16x8 x6 = *(const s16x8*)&X[(size_t)c1.z * NH + 8*lane];
        s16x8 x7 = *(const s16x8*)&X[(size_t)c1.w * NH + 8*lane];
        #pragma unroll
        for (int j = 0; j < 8; ++j) {
            acc[j] += v0.x * bf2f((ushort_t)x0[j]);
            acc[j] += v0.y * bf2f((ushort_t)x1[j]);
            acc[j] += v0.z * bf2f((ushort_t)x2[j]);
            acc[j] += v0.w * bf2f((ushort_t)x3[j]);
            acc[j] += v1.x * bf2f((ushort_t)x4[j]);
            acc[j] += v1.y * bf2f((ushort_t)x5[j]);
            acc[j] += v1.z * bf2f((ushort_t)x6[j]);
            acc[j] += v1.w * bf2f((ushort_t)x7[j]);
        }
    }
    const float* yr = yv + (size_t)i * NH + 8*lane;
    float4 ya = *(const float4*)yr;
    float4 yb = *(const float4*)(yr + 4);
    float4 ba = *(const float4*)&bias[8*lane];
    float4 bb = *(const float4*)&bias[8*lane + 4];
    float v[8];
    v[0] = alpha*acc[0] + ya.x + ba.x; v[1] = alpha*acc[1] + ya.y + ba.y;
    v[2] = alpha*acc[2] + ya.z + ba.z; v[3] = alpha*acc[3] + ya.w + ba.w;
    v[4] = alpha*acc[4] + yb.x + bb.x; v[5] = alpha*acc[5] + yb.y + bb.y;
    v[6] = alpha*acc[6] + yb.z + bb.z; v[7] = alpha*acc[7] + yb.w + bb.w;
    float ss = 0.f;
    #pragma unroll
    for (int j = 0; j < 8; ++j) ss += v[j]*v[j];
    #pragma unroll
    for (int o = 1; o < 64; o <<= 1) ss += __shfl_xor(ss, o, 64);
    float sc = ln ? 1.0f / fmaxf(sqrtf(ss), 1e-12f) : 1.0f;
    s16x8 o;
    #pragma unroll
    for (int j = 0; j < 8; ++j) o[j] = (short)f2bf(v[j] * sc);
    *(s16x8*)&F[(size_t)i*NH + 8*lane] = o;
}

// ================= role: double-hop (A^2 x)_i computed on the fly =================
__device__ void role_dh2(int i, int lane, const int* __restrict__ rc8,
                         const int* __restrict__ rct,
                         const int* __restrict__ ci, const float* __restrict__ vl,
                         const ushort_t* __restrict__ X, float* __restrict__ acc) {
    int cti = rct[i];
    for (int p = 0; p < cti; ++p) {
        int j = ci[i*64 + p];
        float vij = vl[i*64 + p];
        int cj = rc8[j];
        for (int q = 0; q < cj; q += 8) {
            int4   c0 = *(const int4*)&ci[j*64 + q];
            int4   c1 = *(const int4*)&ci[j*64 + q + 4];
            float4 v0 = *(const float4*)&vl[j*64 + q];
            float4 v1 = *(const float4*)&vl[j*64 + q + 4];
            float w0 = vij*v0.x, w1 = vij*v0.y, w2 = vij*v0.z, w3 = vij*v0.w;
            float w4 = vij*v1.x, w5 = vij*v1.y, w6 = vij*v1.z, w7 = vij*v1.w;
            s16x8 x0 = *(const s16x8*)&X[(size_t)c0.x * NH + 8*lane];
            s16x8 x1 = *(const s16x8*)&X[(size_t)c0.y * NH + 8*lane];
            s16x8 x2 = *(const s16x8*)&X[(size_t)c0.z * NH + 8*lane];
            s16x8 x3 = *(const s16x8*)&X[(size_t)c0.w * NH + 8*lane];
            s16x8 x4 = *(const s16x8*)&X[(size_t)c1.x * NH + 8*lane];
            s16x8 x5 = *(const s16x8*)&X[(size_t)c1.y * NH + 8*lane];
            s16x8 x6 = *(const s16x8*)&X[(size_t)c1.z * NH + 8*lane];
            s16x8 x7 = *(const s16x8*)&X[(size_t)c1.w * NH + 8*lane];
            #pragma unroll
            for (int jj = 0; jj < 8; ++jj) {
                acc[jj] += w0 * bf2f((ushort_t)x0[jj]);
                acc[jj] += w1 * bf2f((ushort_t)x1[jj]);
                acc[jj] += w2 * bf2f((ushort_t)x2[jj]);
                acc[jj] += w3 * bf2f((ushort_t)x3[jj]);
                acc[jj] += w4 * bf2f((ushort_t)x4[jj]);
                acc[jj] += w5 * bf2f((ushort_t)x5[jj]);
                acc[jj] += w6 * bf2f((ushort_t)x6[jj]);
                acc[jj] += w7 * bf2f((ushort_t)x7[jj]);
            }
        }
    }
}

// dh plain: Y = A^2 X (bf16 out)
__device__ void role_dh2P(int i, int lane, const int* __restrict__ rc8,
                          const int* __restrict__ rct,
                          const int* __restrict__ ci, const float* __restrict__ vl,
                          const ushort_t* __restrict__ X, ushort_t* __restrict__ Y) {
    float acc[8] = {0,0,0,0,0,0,0,0};
    role_dh2(i, lane, rc8, rct, ci, vl, X, acc);
    s16x8 o;
    #pragma unroll
    for (int j = 0; j < 8; ++j) o[j] = (short)f2bf(acc[j]);
    *(s16x8*)&Y[(size_t)i*NH + 8*lane] = o;
}

// dh final: F = norm(alpha*A^2 X + yv + bias)
__device__ void role_dh2F(int i, int lane, const int* __restrict__ rc8,
                          const int* __restrict__ rct,
                          const int* __restrict__ ci, const float* __restrict__ vl,
                          const ushort_t* __restrict__ X, const float* __restrict__ yv,
                          const float* __restrict__ bias, int ln, float alpha,
                          ushort_t* __restrict__ F) {
    float acc[8] = {0,0,0,0,0,0,0,0};
    role_dh2(i, lane, rc8, rct, ci, vl, X, acc);
    const float* yr = yv + (size_t)i * NH + 8*lane;
    float4 ya = *(const float4*)yr;
    float4 yb = *(const float4*)(yr + 4);
    float4 ba = *(const float4*)&bias[8*lane];
    float4 bb = *(const float4*)&bias[8*lane + 4];
    float v[8];
    v[0] = alpha*acc[0] + ya.x + ba.x; v[1] = alpha*acc[1] + ya.y + ba.y;
    v[2] = alpha*acc[2] + ya.z + ba.z; v[3] = alpha*acc[3] + ya.w + ba.w;
    v[4] = alpha*acc[4] + yb.x + bb.x; v[5] = alpha*acc[5] + yb.y + bb.y;
    v[6] = alpha*acc[6] + yb.z + bb.z; v[7] = alpha*acc[7] + yb.w + bb.w;
    float ss = 0.f;
    #pragma unroll
    for (int j = 0; j < 8; ++j) ss += v[j]*v[j];
    #pragma unroll
    for (int o = 1; o < 64; o <<= 1) ss += __shfl_xor(ss, o, 64);
    float sc = ln ? 1.0f / fmaxf(sqrtf(ss), 1e-12f) : 1.0f;
    s16x8 o;
    #pragma unroll
    for (int j = 0; j < 8; ++j) o[j] = (short)f2bf(v[j] * sc);
    *(s16x8*)&F[(size_t)i*NH + 8*lane] = o;
}

// ================= phase kernels =================
// P1: build | featbf | labelbits | Wt x6 | alphas
__global__ __launch_bounds__(256) void k_setup(const float* __restrict__ adj,
        const float* __restrict__ features, ushort_t* __restrict__ featb,
        const float* __restrict__ y, u64* __restrict__ LC,
        const float* __restrict__ W0, const float* __restrict__ W1_0,
        const float* __restrict__ W1_1,
        ushort_t* __restrict__ Wh0t, ushort_t* __restrict__ Wy0t,
        ushort_t* __restrict__ Wh1t, ushort_t* __restrict__ Wy1t,
        ushort_t* __restrict__ Wh2t, ushort_t* __restrict__ Wy2t,
        const float* __restrict__ alphas, float* __restrict__ a_sm,
        u64* __restrict__ B1, int* __restrict__ rowcnt, int* __restrict__ rowcnt_true,
        int* __restrict__ colidx, float* __restrict__ vals) {
    __shared__ __align__(16) char smem[4352];
    int b = blockIdx.x, t = threadIdx.x;
    int wid = t >> 6, l = t & 63;
    if (b < 1024) {
        role_build(b*4 + wid, l, adj, B1, rowcnt, rowcnt_true, colidx, vals);
    } else if (b < 5120) {
        int base = (b - 1024) * 1024 + t * 4;
        float4 v = *(const float4*)&features[base];
        ushort4 o;
        o.x = f2bf(v.x); o.y = f2bf(v.y); o.z = f2bf(v.z); o.w = f2bf(v.w);
        *(ushort4*)&featb[base] = o;
    } else if (b < 5136) {
        int w = (b - 5120) * 4 + wid;
        const float* yr = y + (size_t)(w*64 + l) * NC;
        for (int c = 0; c < NC; ++c) {
            u64 m = __ballot(yr[c] > 0.5f);
            if (l == c) LC[c*64 + w] = m;
        }
    } else if (b < 5648) { role_wt(W0,   Wh0t, 0,    NF, b - 5136, smem, t); }
    else if (b < 5696)   { role_wt(W0,   Wy0t, NF,   96, b - 5648, smem, t); }
    else if (b < 5952)   { role_wt(W1_0, Wh1t, 0,    NH, b - 5696, smem, t); }
    else if (b < 6000)   { role_wt(W1_0, Wy1t, NH,   96, b - 5952, smem, t); }
    else if (b < 6256)   { role_wt(W1_1, Wh2t, 0,    NH, b - 6000, smem, t); }
    else if (b < 6304)   { role_wt(W1_1, Wy2t, NH,   96, b - 6256, smem, t); }
    else {
        if (t == 0) {
            for (int i = 0; i < 3; ++i) {
                float m = -1e30f;
                for (int j = 0; j < 5; ++j) m = fmaxf(m, alphas[i*5+j]);
                float e[5]; float s = 0.f;
                for (int j = 0; j < 5; ++j) { e[j] = expf(alphas[i*5+j] - m); s += e[j]; }
                for (int j = 0; j < 5; ++j) a_sm[i*5+j] = e[j] / s;
            }
        }
    }
}

// P2: z0 gemm (bf16 A) | bsq(B1,B1->B2) | btrans(B1)
__global__ __launch_bounds__(256) void k_p2(const ushort_t* __restrict__ featb,
        const ushort_t* __restrict__ Wh0t, ushort_t* __restrict__ zb,
        const u64* __restrict__ B1, u64* __restrict__ B2, u64* __restrict__ B1T) {
    __shared__ __align__(16) char smem[10240];
    int b = blockIdx.x, t = threadIdx.x;
    int wid = t >> 6, l = t & 63;
    if (b < 512)       role_gemm(b, t, smem, featb, nullptr, NF, Wh0t, NF, zb, nullptr);
    else if (b < 4608) role_bsq(b - 512, t, smem, B1, B1, B2);
    else               role_btrans((b - 4608)*4 + wid, wid, l, smem, B1, B1T);
}

// P3: bsq(B1,B2->B3) | btrans(B2) | ymat0
__global__ __launch_bounds__(256) void k_p3(const u64* __restrict__ B1,
        const u64* __restrict__ B2, u64* __restrict__ B3, u64* __restrict__ B2T,
        const u64* __restrict__ B1T, const u64* __restrict__ LC,
        const float* __restrict__ a_sm, ushort_t* __restrict__ y0c) {
    __shared__ __align__(16) char smem[24576];
    int b = blockIdx.x, t = threadIdx.x;
    int wid = t >> 6, l = t & 63;
    if (b < 4096)      role_bsq(b, t, smem, B1, B2, B3);
    else if (b < 5120) role_btrans((b - 4096)*4 + wid, wid, l, smem, B2, B2T);
    else               role_ymat((b - 5120)*8, t, smem, B1, B1T, LC, a_sm, y0c);
}

// P4: ygemm0 | ymat1 | bsq(B1,B3->B4)
__global__ __launch_bounds__(256) void k_p4(const ushort_t* __restrict__ y0c,
        const ushort_t* __restrict__ Wy0t, float* __restrict__ yv0,
        const u64* __restrict__ B2, const u64* __restrict__ B2T,
        const u64* __restrict__ LC, const float* __restrict__ a_sm,
        ushort_t* __restrict__ y1c,
        const u64* __restrict__ B1, const u64* __restrict__ B3, u64* __restrict__ B4) {
    __shared__ __align__(16) char smem[24576];
    int b = blockIdx.x, t = threadIdx.x;
    if (b < 512)       role_gemm(b, t, smem, y0c, nullptr, 96, Wy0t, 96, nullptr, yv0);
    else if (b < 1024) role_ymat((b - 512)*8, t, smem, B2, B2T, LC, a_sm + 5, y1c);
    else               role_bsq(b - 1024, t, smem, B1, B3, B4);
}

// P5: spmm0F (adj@z0 -> f1) | btrans(B4) | ygemm1
__global__ __launch_bounds__(256) void k_p5(const int* __restrict__ rc,
        const int* __restrict__ ci, const float* __restrict__ vl,
        const ushort_t* __restrict__ zb, const float* __restrict__ yv0,
        const float* __restrict__ b0, const int* __restrict__ lnflag,
        const float* __restrict__ a_sm, ushort_t* __restrict__ f1,
        const u64* __restrict__ B4, u64* __restrict__ B4T,
        const ushort_t* __restrict__ y1c, const ushort_t* __restrict__ Wy1t,
        float* __restrict__ yv1) {
    __shared__ __align__(16) char smem[10240];
    int b = blockIdx.x, t = threadIdx.x;
    int wid = t >> 6, l = t & 63;
    if (b < 1024)
        role_spmmF(b*4 + wid, l, rc, ci, vl, zb, yv0, b0, *lnflag, a_sm[0], f1);
    else if (b < 2048)
        role_btrans((b - 1024)*4 + wid, wid, l, smem, B4, B4T);
    else
        role_gemm(b - 2048, t, smem, y1c, nullptr, 96, Wy1t, 96, nullptr, yv1);
}

// P6: gemm z1 = f1 @ Wh1 | ymat2
__global__ __launch_bounds__(256) void k_p6(const ushort_t* __restrict__ f1,
        const ushort_t* __restrict__ Wh1t, ushort_t* __restrict__ zb,
        const u64* __restrict__ B4, const u64* __restrict__ B4T,
        const u64* __restrict__ LC, const float* __restrict__ a_sm,
        ushort_t* __restrict__ y2c) {
    __shared__ __align__(16) char smem[24576];
    int b = blockIdx.x, t = threadIdx.x;
    if (b < 512) role_gemm(b, t, smem, f1, nullptr, NH, Wh1t, NH, zb, nullptr);
    else         role_ymat((b - 512)*8, t, smem, B4, B4T, LC, a_sm + 10, y2c);
}

// P7: dh_F (A^2 zb -> f2) | ygemm2
__global__ __launch_bounds__(256) void k_p7(const int* __restrict__ rc8,
        const int* __restrict__ rct,
        const int* __restrict__ ci, const float* __restrict__ vl,
        const ushort_t* __restrict__ zb, const float* __restrict__ yv1,
        const float* __restrict__ b1_0, const int* __restrict__ lnflag,
        const float* __restrict__ a_sm, ushort_t* __restrict__ f2,
        const ushort_t* __restrict__ y2c, const ushort_t* __restrict__ Wy2t,
        float* __restrict__ yv2) {
    __shared__ __align__(16) char smem[10240];
    int b = blockIdx.x, t = threadIdx.x;
    int wid = t >> 6, l = t & 63;
    if (b < 1024)
        role_dh2F(b*4 + wid, l, rc8, rct, ci, vl, zb, yv1, b1_0, *lnflag, a_sm[5], f2);
    else
        role_gemm(b - 1024, t, smem, y2c, nullptr, 96, Wy2t, 96, nullptr, yv2);
}

__global__ __launch_bounds__(256) void k_gemmz(const ushort_t* __restrict__ A,
        const ushort_t* __restrict__ Bt, ushort_t* __restrict__ C, int K) {
    __shared__ __align__(16) char smem[10240];
    role_gemm(blockIdx.x, threadIdx.x, smem, A, nullptr, K, Bt, K, C, nullptr);
}

// P9: dh plain (A^2 zb -> ub)
__global__ __launch_bounds__(256) void k_dh(const int* __restrict__ rc8,
        const int* __restrict__ rct,
        const int* __restrict__ ci, const float* __restrict__ vl,
        const ushort_t* __restrict__ X, ushort_t* __restrict__ Y) {
    role_dh2P(blockIdx.x*4 + (threadIdx.x >> 6), threadIdx.x & 63, rc8, rct, ci, vl, X, Y);
}

// P10: dh_F (A^2 ub -> f3)
__global__ __launch_bounds__(256) void k_dhF(const int* __restrict__ rc8,
        const int* __restrict__ rct,
        const int* __restrict__ ci, const float* __restrict__ vl,
        const ushort_t* __restrict__ X, const float* __restrict__ yv,
        const float* __restrict__ bias, const int* __restrict__ lnflag,
        const float* __restrict__ a_sm, int ai, ushort_t* __restrict__ F) {
    role_dh2F(blockIdx.x*4 + (threadIdx.x >> 6), threadIdx.x & 63, rc8, rct, ci, vl,
              X, yv, bias, *lnflag, a_sm[ai], F);
}

// ================= final: [relu(featb) | relu(max(f1,f2,f3))] @ W2 + b2 -> log_softmax ===
__global__ __launch_bounds__(256) void k_final(const ushort_t* __restrict__ featb,
        const ushort_t* __restrict__ f1, const ushort_t* __restrict__ f2,
        const ushort_t* __restrict__ f3, const float* __restrict__ W2,
        const float* __restrict__ b2, float* __restrict__ out) {
    int rb = blockIdx.x * 8;
    int t = threadIdx.x;
    __shared__ float rows[8][NF + NH];
    __shared__ float part[8][8][32];
    #pragma unroll
    for (int r = 0; r < 8; ++r) {
        ushort4 v = *(const ushort4*)&featb[(size_t)(rb + r) * NF + t * 4];
        rows[r][t*4+0] = fmaxf(bf2f(v.x), 0.f);
        rows[r][t*4+1] = fmaxf(bf2f(v.y), 0.f);
        rows[r][t*4+2] = fmaxf(bf2f(v.z), 0.f);
        rows[r][t*4+3] = fmaxf(bf2f(v.w), 0.f);
    }
    #pragma unroll
    for (int q = 0; q < 2; ++q) {
        int ch = t*2 + q;
        int rr = ch >> 6, k8 = (ch & 63) * 8;
        s16x8 a = *(const s16x8*)&f1[(size_t)(rb + rr)*NH + k8];
        s16x8 bq = *(const s16x8*)&f2[(size_t)(rb + rr)*NH + k8];
        s16x8 cq = *(const s16x8*)&f3[(size_t)(rb + rr)*NH + k8];
        #pragma unroll
        for (int j = 0; j < 8; ++j) {
            float m = fmaxf(fmaxf(bf2f((ushort_t)a[j]), bf2f((ushort_t)bq[j])),
                            bf2f((ushort_t)cq[j]));
            rows[rr][NF + k8 + j] = fmaxf(m, 0.f);
        }
    }
    __syncthreads();
    int c = t & 31, g = t >> 5;
    float acc[8] = {0,0,0,0,0,0,0,0};
    for (int k = g * 192; k < (g + 1) * 192; ++k) {
        float w = W2[(size_t)k * NC + c];
        #pragma unroll
        for (int r = 0; r < 8; ++r) acc[r] += rows[r][k] * w;
    }
    #pragma unroll
    for (int r = 0; r < 8; ++r) part[g][r][c] = acc[r];
    __syncthreads();
    int r = g;
    float lg = b2[c];
    #pragma unroll
    for (int gg = 0; gg < 8; ++gg) lg += part[gg][r][c];
    float m = lg;
    #pragma unroll
    for (int o = 16; o > 0; o >>= 1) m = fmaxf(m, __shfl_xor(m, o, 32));
    float e = expf(lg - m), s = e;
    #pragma unroll
    for (int o = 16; o > 0; o >>= 1) s += __shfl_xor(s, o, 32);
    out[(size_t)(rb + r) * NC + c] = lg - m - logf(s);
}

extern "C" void kernel_launch(void* const* d_in, const int* in_sizes, int n_in,
                              void* d_out, int out_size, void* d_ws, size_t ws_size,
                              hipStream_t stream) {
    const float* adj      = (const float*)d_in[0];
    const float* features = (const float*)d_in[1];
    const float* y        = (const float*)d_in[2];
    const float* W0       = (const float*)d_in[3];
    const float* b0       = (const float*)d_in[4];
    const float* W1_0     = (const float*)d_in[5];
    const float* b1_0     = (const float*)d_in[6];
    const float* W1_1     = (const float*)d_in[7];
    const float* b1_1     = (const float*)d_in[8];
    const float* W2       = (const float*)d_in[9];
    const float* b2       = (const float*)d_in[10];
    const float* alphas   = (const float*)d_in[11];
    const int*   lnflag   = (const int*)d_in[12];
    float* out = (float*)d_out;

    char* ws = (char*)d_ws;
    size_t off = 0;
    auto alloc = [&](size_t bytes) -> char* {
        char* p = ws + off;
        off = (off + bytes + 255) & ~(size_t)255;
        return p;
    };
    float* a_sm        = (float*)alloc(16 * 4);
    int*   rowcnt      = (int*)alloc((size_t)NN * 4);
    int*   rowcnt_true = (int*)alloc((size_t)NN * 4);
    int*   colidx      = (int*)alloc((size_t)NN * 64 * 4);
    float* vals        = (float*)alloc((size_t)NN * 64 * 4);
    u64* B1  = (u64*)alloc((size_t)NN * 64 * 8);
    u64* B2  = (u64*)alloc((size_t)NN * 64 * 8);
    u64* B3  = (u64*)alloc((size_t)NN * 64 * 8);
    u64* B4  = (u64*)alloc((size_t)NN * 64 * 8);
    u64* B1T = (u64*)alloc((size_t)NN * 64 * 8);
    u64* B2T = (u64*)alloc((size_t)NN * 64 * 8);
    u64* B4T = (u64*)alloc((size_t)NN * 64 * 8);
    u64* LC  = (u64*)alloc((size_t)NC * 64 * 8);
    ushort_t* featb = (ushort_t*)alloc((size_t)NN * NF * 2);
    ushort_t* Wh0t = (ushort_t*)alloc((size_t)NH * NF * 2);
    ushort_t* Wh1t = (ushort_t*)alloc((size_t)NH * NH * 2);
    ushort_t* Wh2t = (ushort_t*)alloc((size_t)NH * NH * 2);
    ushort_t* Wy0t = (ushort_t*)alloc((size_t)NH * 96 * 2);
    ushort_t* Wy1t = (ushort_t*)alloc((size_t)NH * 96 * 2);
    ushort_t* Wy2t = (ushort_t*)alloc((size_t)NH * 96 * 2);
    ushort_t* y0c  = (ushort_t*)alloc((size_t)NN * 96 * 2);
    ushort_t* y1c  = (ushort_t*)alloc((size_t)NN * 96 * 2);
    ushort_t* y2c  = (ushort_t*)alloc((size_t)NN * 96 * 2);
    float* yv0 = (float*)alloc((size_t)NN * NH * 4);
    float* yv1 = (float*)alloc((size_t)NN * NH * 4);
    float* yv2 = (float*)alloc((size_t)NN * NH * 4);
    ushort_t* zb = (ushort_t*)alloc((size_t)NN * NH * 2);
    ushort_t* ub = (ushort_t*)alloc((size_t)NN * NH * 2);
    ushort_t* f1 = (ushort_t*)alloc((size_t)NN * NH * 2);
    ushort_t* f2 = (ushort_t*)alloc((size_t)NN * NH * 2);
    ushort_t* f3 = (ushort_t*)alloc((size_t)NN * NH * 2);

    // P1: build | featbf | LC | W transposes | alphas
    k_setup<<<6305, 256, 0, stream>>>(adj, features, featb, y, LC, W0, W1_0, W1_1,
                                      Wh0t, Wy0t, Wh1t, Wy1t, Wh2t, Wy2t,
                                      alphas, a_sm, B1, rowcnt, rowcnt_true,
                                      colidx, vals);
    // P2: z0 gemm (bf16) | bsq B2 | btrans B1
    k_p2<<<5632, 256, 0, stream>>>(featb, Wh0t, zb, B1, B2, B1T);
    // P3: bsq B3 | btrans B2 | ymat0
    k_p3<<<5632, 256, 0, stream>>>(B1, B2, B3, B2T, B1T, LC, a_sm, y0c);
    // P4: ygemm0 | ymat1 | bsq B4
    k_p4<<<5120, 256, 0, stream>>>(y0c, Wy0t, yv0, B2, B2T, LC, a_sm, y1c, B1, B3, B4);
    // P5: spmm0F -> f1 | btrans B4 | ygemm1
    k_p5<<<2560, 256, 0, stream>>>(rowcnt, colidx, vals, zb, yv0, b0, lnflag, a_sm,
                                   f1, B4, B4T, y1c, Wy1t, yv1);
    // P6: z1 gemm | ymat2
    k_p6<<<1024, 256, 0, stream>>>(f1, Wh1t, zb, B4, B4T, LC, a_sm, y2c);
    // P7: dh_F (A^2 zb -> f2) | ygemm2
    k_p7<<<1536, 256, 0, stream>>>(rowcnt, rowcnt_true, colidx, vals, zb, yv1, b1_0,
                                   lnflag, a_sm, f2, y2c, Wy2t, yv2);
    // P8: z2 gemm
    k_gemmz<<<512, 256, 0, stream>>>(f2, Wh2t, zb, NH);
    // P9: dh (A^2 zb -> ub)
    k_dh<<<1024, 256, 0, stream>>>(rowcnt, rowcnt_true, colidx, vals, zb, ub);
    // P10: dh_F (A^2 ub -> f3)
    k_dhF<<<1024, 256, 0, stream>>>(rowcnt, rowcnt_true, colidx, vals, ub, yv2, b1_1,
                                    lnflag, a_sm, 10, f3);
    // P11: final
    k_final<<<512, 256, 0, stream>>>(featb, f1, f2, f3, W2, b2, out);
}

// Round 12
// 185.924 us; speedup vs baseline: 1.3444x; 1.3444x over previous
//
#include <hip/hip_runtime.h>
#include <hip/hip_bf16.h>
#include <math.h>

typedef unsigned long long u64;
typedef unsigned short ushort_t;
typedef float f32x4 __attribute__((ext_vector_type(4)));
typedef short s16x8 __attribute__((ext_vector_type(8)));

#define NN 4096
#define NF 1024
#define NH 512
#define NC 32
#define LDP 40

__device__ inline float bf2f(ushort_t u) {
    unsigned int v = ((unsigned int)u) << 16;
    return __uint_as_float(v);
}
__device__ inline ushort_t f2bf(float f) {
    __hip_bfloat16 h = __float2bfloat16(f);
    return *(ushort_t*)&h;
}

// ================= role: build one adj row (wave-wide), ELL padded to 8 =================
__device__ void role_build(int i, int l, const float* __restrict__ adj,
                           u64* __restrict__ B1, int* __restrict__ rowcnt,
                           int* __restrict__ colidx, float* __restrict__ vals) {
    const float* row = adj + (size_t)i * NN + l * 64;
    const float4* row4 = (const float4*)row;
    u64 w = 0;
    #pragma unroll
    for (int k = 0; k < 16; ++k) {
        float4 v = row4[k];
        if (v.x > 0.f) w |= 1ULL << (4*k + 0);
        if (v.y > 0.f) w |= 1ULL << (4*k + 1);
        if (v.z > 0.f) w |= 1ULL << (4*k + 2);
        if (v.w > 0.f) w |= 1ULL << (4*k + 3);
    }
    B1[(size_t)i*64 + l] = w;
    int cnt = __popcll(w);
    int pre = cnt;
    #pragma unroll
    for (int o = 1; o < 64; o <<= 1) {
        int u = __shfl_up(pre, o, 64);
        if (l >= o) pre += u;
    }
    int excl = pre - cnt;
    int total = __shfl(pre, 63, 64);
    u64 ww = w;
    int idx = excl;
    while (ww) {
        int b = __ffsll((unsigned long long)ww) - 1;
        ww &= ww - 1;
        if (idx < 64) {
            colidx[i*64 + idx] = l*64 + b;
            vals[i*64 + idx] = row[b];
        }
        ++idx;
    }
    int tot = total < 64 ? total : 64;
    for (int s = tot + l; s < 64; s += 64) {
        colidx[i*64 + s] = 0;
        vals[i*64 + s] = 0.f;
    }
    if (l == 0) {
        int r8 = (tot + 7) & ~7;
        rowcnt[i] = r8 < 64 ? r8 : 64;
    }
}

// ================= role: W-transpose tile 32x32, fp32 [K][NH] -> bf16 [NH][Kd] =========
__device__ void role_wt(const float* __restrict__ W, ushort_t* __restrict__ Wt,
                        int ksrc0, int Kd, int idx, char* smem, int t) {
    float (*tile)[33] = (float(*)[33])smem;
    int ktiles = Kd >> 5;
    int kb = (idx % ktiles) * 32, nb = (idx / ktiles) * 32;
    int tc = t & 31, tr8 = t >> 5;
    for (int r = tr8; r < 32; r += 8)
        tile[r][tc] = W[(size_t)(ksrc0 + kb + r) * NH + nb + tc];
    __syncthreads();
    for (int r = tr8; r < 32; r += 8)
        Wt[(size_t)(nb + r) * Kd + kb + tc] = f2bf(tile[tc][r]);
}

// ================= role: boolean product row =================
__device__ void role_bsq(int i, int t, char* smem, const u64* __restrict__ Bidx,
                         const u64* __restrict__ Bdat, u64* __restrict__ Bout) {
    u64* ridx = (u64*)smem;
    u64* part = ridx + 64;
    int wid = t >> 6, lane = t & 63;
    if (t < 64) ridx[t] = Bidx[(size_t)i*64 + t];
    __syncthreads();
    u64 acc = 0;
    for (int u = wid*16; u < wid*16 + 16; ++u) {
        u64 w = ridx[u];
        while (w) {
            int k = u*64 + (__ffsll((unsigned long long)w) - 1);
            w &= (w - 1);
            acc |= Bdat[(size_t)k*64 + lane];
        }
    }
    part[wid*64 + lane] = acc;
    __syncthreads();
    if (t < 64) Bout[(size_t)i*64 + t] = part[t] | part[64+t] | part[128+t] | part[192+t];
}

// ================= role: bit transpose, one 64x64 tile per wave =================
__device__ void role_btrans(int tb, int wid, int l, char* smem,
                            const u64* __restrict__ B, u64* __restrict__ BT) {
    u64* ld = ((u64*)smem) + wid*64;
    int I = tb >> 6, J = tb & 63;
    ld[l] = B[(size_t)(I*64 + l)*64 + J];
    __syncthreads();
    u64 out = 0;
    #pragma unroll
    for (int r = 0; r < 64; ++r) out |= ((ld[r] >> l) & 1ULL) << r;
    BT[(size_t)(J*64 + l)*64 + I] = out;
}

// ================= role: ymat -> yc [NN][96] bf16 (8 rows/block) =================
__device__ void role_ymat(int rb, int t, char* smem, const u64* __restrict__ B,
                          const u64* __restrict__ BT, const u64* __restrict__ LC,
                          const float* __restrict__ asp, ushort_t* __restrict__ yc) {
    u64* LCt   = (u64*)smem;
    u64* rows  = LCt + 64*32;
    u64* rowsT = rows + 8*64;
    for (int k = t; k < 2048; k += 256) {
        int c = k >> 6, w = k & 63;
        LCt[w*32 + c] = LC[k];
    }
    for (int k = t; k < 512; k += 256) {
        int r = k >> 6, w = k & 63;
        rows[r*64 + w]  = B[(size_t)(rb + r)*64 + w];
        rowsT[r*64 + w] = BT[(size_t)(rb + r)*64 + w];
    }
    __syncthreads();
    int wid = t >> 6, lane = t & 63;
    int h = lane >> 5, c = lane & 31;
    int r = wid * 2 + h;
    int co = 0, ci = 0;
    #pragma unroll
    for (int w = 0; w < 64; ++w) {
        u64 lc = LCt[w*32 + c];
        co += __popcll(rows[r*64 + w]  & lc);
        ci += __popcll(rowsT[r*64 + w] & lc);
    }
    float a1 = asp[1], a2 = asp[2], a3 = asp[3];
    size_t i = rb + r;
    yc[i*96 + c]      = f2bf(a1 * (float)co);
    yc[i*96 + 32 + c] = f2bf(a2 * (float)ci);
    yc[i*96 + 64 + c] = f2bf(a3 * (float)(co + ci));
}

// ================= role: MFMA GEMM 64x64 tile, N=512, flexible A/C formats =========
__device__ void role_gemm(int bx, int tid, char* smem, const ushort_t* __restrict__ Abf,
                          const float* __restrict__ Af, int Ka,
                          const ushort_t* __restrict__ Bt, int K,
                          ushort_t* __restrict__ Cb, float* __restrict__ Cf) {
    ushort_t* As = (ushort_t*)smem;
    ushort_t* Bs = As + 64*LDP;
    int xcd = bx & 7, rest = bx >> 3;
    int nt = rest & 7, mt = (rest >> 3) * 8 + xcd;
    int bm = mt * 64, bn = nt * 64;
    int srow = tid >> 2, scol = (tid & 3) * 8;
    int wid = tid >> 6, lane = tid & 63;
    int fr = lane & 15, hi2 = lane >> 4, fk = hi2 * 8;
    f32x4 acc[4] = {{0,0,0,0},{0,0,0,0},{0,0,0,0},{0,0,0,0}};
    for (int k0 = 0; k0 < K; k0 += 32) {
        if (Abf) {
            *(s16x8*)&As[srow * LDP + scol] =
                *(const s16x8*)&Abf[(size_t)(bm + srow) * Ka + k0 + scol];
        } else {
            const float* ap = &Af[(size_t)(bm + srow) * Ka + k0 + scol];
            float4 a0 = *(const float4*)ap;
            float4 a1 = *(const float4*)(ap + 4);
            s16x8 o;
            o[0] = (short)f2bf(a0.x); o[1] = (short)f2bf(a0.y);
            o[2] = (short)f2bf(a0.z); o[3] = (short)f2bf(a0.w);
            o[4] = (short)f2bf(a1.x); o[5] = (short)f2bf(a1.y);
            o[6] = (short)f2bf(a1.z); o[7] = (short)f2bf(a1.w);
            *(s16x8*)&As[srow * LDP + scol] = o;
        }
        *(s16x8*)&Bs[srow * LDP + scol] =
            *(const s16x8*)&Bt[(size_t)(bn + srow) * K + k0 + scol];
        __syncthreads();
        s16x8 af = *(const s16x8*)&As[(wid * 16 + fr) * LDP + fk];
        #pragma unroll
        for (int j = 0; j < 4; ++j) {
            s16x8 bfv = *(const s16x8*)&Bs[(j * 16 + fr) * LDP + fk];
            acc[j] = __builtin_amdgcn_mfma_f32_16x16x32_bf16(af, bfv, acc[j], 0, 0, 0);
        }
        __syncthreads();
    }
    int drow = bm + wid * 16 + hi2 * 4;
    #pragma unroll
    for (int j = 0; j < 4; ++j) {
        int col = bn + j * 16 + fr;
        #pragma unroll
        for (int r = 0; r < 4; ++r) {
            if (Cb) Cb[(size_t)(drow + r) * NH + col] = f2bf(acc[j][r]);
            else    Cf[(size_t)(drow + r) * NH + col] = acc[j][r];
        }
    }
}

// ================= role: spmm pass (512-wide bf16, 8 gathers in flight) =========
__device__ void role_spmm(int i, int lane, const int* __restrict__ rc,
                          const int* __restrict__ ci, const float* __restrict__ vl,
                          const ushort_t* __restrict__ X, ushort_t* __restrict__ Y) {
    int cnt = rc[i];
    float acc[8] = {0,0,0,0,0,0,0,0};
    for (int p = 0; p < cnt; p += 8) {
        int4   c0 = *(const int4*)&ci[i*64 + p];
        int4   c1 = *(const int4*)&ci[i*64 + p + 4];
        float4 v0 = *(const float4*)&vl[i*64 + p];
        float4 v1 = *(const float4*)&vl[i*64 + p + 4];
        s16x8 x0 = *(const s16x8*)&X[(size_t)c0.x * NH + 8*lane];
        s16x8 x1 = *(const s16x8*)&X[(size_t)c0.y * NH + 8*lane];
        s16x8 x2 = *(const s16x8*)&X[(size_t)c0.z * NH + 8*lane];
        s16x8 x3 = *(const s16x8*)&X[(size_t)c0.w * NH + 8*lane];
        s16x8 x4 = *(const s16x8*)&X[(size_t)c1.x * NH + 8*lane];
        s16x8 x5 = *(const s16x8*)&X[(size_t)c1.y * NH + 8*lane];
        s16x8 x6 = *(const s16x8*)&X[(size_t)c1.z * NH + 8*lane];
        s16x8 x7 = *(const s16x8*)&X[(size_t)c1.w * NH + 8*lane];
        #pragma unroll
        for (int j = 0; j < 8; ++j) {
            acc[j] += v0.x * bf2f((ushort_t)x0[j]);
            acc[j] += v0.y * bf2f((ushort_t)x1[j]);
            acc[j] += v0.z * bf2f((ushort_t)x2[j]);
            acc[j] += v0.w * bf2f((ushort_t)x3[j]);
            acc[j] += v1.x * bf2f((ushort_t)x4[j]);
            acc[j] += v1.y * bf2f((ushort_t)x5[j]);
            acc[j] += v1.z * bf2f((ushort_t)x6[j]);
            acc[j] += v1.w * bf2f((ushort_t)x7[j]);
        }
    }
    s16x8 o;
    #pragma unroll
    for (int j = 0; j < 8; ++j) o[j] = (short)f2bf(acc[j]);
    *(s16x8*)&Y[(size_t)i*NH + 8*lane] = o;
}

// ================= role: final spmm pass: + alpha, yv, bias; normalize; write feats ===
__device__ void role_spmmF(int i, int lane, const int* __restrict__ rc,
                           const int* __restrict__ ci, const float* __restrict__ vl,
                           const ushort_t* __restrict__ X, const float* __restrict__ yv,
                           const float* __restrict__ bias, int ln, float alpha,
                           ushort_t* __restrict__ F) {
    int cnt = rc[i];
    float acc[8] = {0,0,0,0,0,0,0,0};
    for (int p = 0; p < cnt; p += 8) {
        int4   c0 = *(const int4*)&ci[i*64 + p];
        int4   c1 = *(const int4*)&ci[i*64 + p + 4];
        float4 v0 = *(const float4*)&vl[i*64 + p];
        float4 v1 = *(const float4*)&vl[i*64 + p + 4];
        s16x8 x0 = *(const s16x8*)&X[(size_t)c0.x * NH + 8*lane];
        s16x8 x1 = *(const s16x8*)&X[(size_t)c0.y * NH + 8*lane];
        s16x8 x2 = *(const s16x8*)&X[(size_t)c0.z * NH + 8*lane];
        s16x8 x3 = *(const s16x8*)&X[(size_t)c0.w * NH + 8*lane];
        s16x8 x4 = *(const s16x8*)&X[(size_t)c1.x * NH + 8*lane];
        s16x8 x5 = *(const s16x8*)&X[(size_t)c1.y * NH + 8*lane];
        s16x8 x6 = *(const s16x8*)&X[(size_t)c1.z * NH + 8*lane];
        s16x8 x7 = *(const s16x8*)&X[(size_t)c1.w * NH + 8*lane];
        #pragma unroll
        for (int j = 0; j < 8; ++j) {
            acc[j] += v0.x * bf2f((ushort_t)x0[j]);
            acc[j] += v0.y * bf2f((ushort_t)x1[j]);
            acc[j] += v0.z * bf2f((ushort_t)x2[j]);
            acc[j] += v0.w * bf2f((ushort_t)x3[j]);
            acc[j] += v1.x * bf2f((ushort_t)x4[j]);
            acc[j] += v1.y * bf2f((ushort_t)x5[j]);
            acc[j] += v1.z * bf2f((ushort_t)x6[j]);
            acc[j] += v1.w * bf2f((ushort_t)x7[j]);
        }
    }
    const float* yr = yv + (size_t)i * NH + 8*lane;
    float4 ya = *(const float4*)yr;
    float4 yb = *(const float4*)(yr + 4);
    float4 ba = *(const float4*)&bias[8*lane];
    float4 bb = *(const float4*)&bias[8*lane + 4];
    float v[8];
    v[0] = alpha*acc[0] + ya.x + ba.x; v[1] = alpha*acc[1] + ya.y + ba.y;
    v[2] = alpha*acc[2] + ya.z + ba.z; v[3] = alpha*acc[3] + ya.w + ba.w;
    v[4] = alpha*acc[4] + yb.x + bb.x; v[5] = alpha*acc[5] + yb.y + bb.y;
    v[6] = alpha*acc[6] + yb.z + bb.z; v[7] = alpha*acc[7] + yb.w + bb.w;
    float ss = 0.f;
    #pragma unroll
    for (int j = 0; j < 8; ++j) ss += v[j]*v[j];
    #pragma unroll
    for (int o = 1; o < 64; o <<= 1) ss += __shfl_xor(ss, o, 64);
    float sc = ln ? 1.0f / fmaxf(sqrtf(ss), 1e-12f) : 1.0f;
    s16x8 o;
    #pragma unroll
    for (int j = 0; j < 8; ++j) o[j] = (short)f2bf(v[j] * sc);
    *(s16x8*)&F[(size_t)i*NH + 8*lane] = o;
}

// ================= phase kernels =================
// P1: build | featbf | labelbits | Wt x6 | alphas
__global__ __launch_bounds__(256) void k_setup(const float* __restrict__ adj,
        const float* __restrict__ features, ushort_t* __restrict__ featb,
        const float* __restrict__ y, u64* __restrict__ LC,
        const float* __restrict__ W0, const float* __restrict__ W1_0,
        const float* __restrict__ W1_1,
        ushort_t* __restrict__ Wh0t, ushort_t* __restrict__ Wy0t,
        ushort_t* __restrict__ Wh1t, ushort_t* __restrict__ Wy1t,
        ushort_t* __restrict__ Wh2t, ushort_t* __restrict__ Wy2t,
        const float* __restrict__ alphas, float* __restrict__ a_sm,
        u64* __restrict__ B1, int* __restrict__ rowcnt,
        int* __restrict__ colidx, float* __restrict__ vals) {
    __shared__ __align__(16) char smem[4352];
    int b = blockIdx.x, t = threadIdx.x;
    int wid = t >> 6, l = t & 63;
    if (b < 1024) {
        role_build(b*4 + wid, l, adj, B1, rowcnt, colidx, vals);
    } else if (b < 5120) {
        int base = (b - 1024) * 1024 + t * 4;
        float4 v = *(const float4*)&features[base];
        ushort4 o;
        o.x = f2bf(v.x); o.y = f2bf(v.y); o.z = f2bf(v.z); o.w = f2bf(v.w);
        *(ushort4*)&featb[base] = o;
    } else if (b < 5136) {
        int w = (b - 5120) * 4 + wid;
        const float* yr = y + (size_t)(w*64 + l) * NC;
        for (int c = 0; c < NC; ++c) {
            u64 m = __ballot(yr[c] > 0.5f);
            if (l == c) LC[c*64 + w] = m;
        }
    } else if (b < 5648) { role_wt(W0,   Wh0t, 0,    NF, b - 5136, smem, t); }
    else if (b < 5696)   { role_wt(W0,   Wy0t, NF,   96, b - 5648, smem, t); }
    else if (b < 5952)   { role_wt(W1_0, Wh1t, 0,    NH, b - 5696, smem, t); }
    else if (b < 6000)   { role_wt(W1_0, Wy1t, NH,   96, b - 5952, smem, t); }
    else if (b < 6256)   { role_wt(W1_1, Wh2t, 0,    NH, b - 6000, smem, t); }
    else if (b < 6304)   { role_wt(W1_1, Wy2t, NH,   96, b - 6256, smem, t); }
    else {
        if (t == 0) {
            for (int i = 0; i < 3; ++i) {
                float m = -1e30f;
                for (int j = 0; j < 5; ++j) m = fmaxf(m, alphas[i*5+j]);
                float e[5]; float s = 0.f;
                for (int j = 0; j < 5; ++j) { e[j] = expf(alphas[i*5+j] - m); s += e[j]; }
                for (int j = 0; j < 5; ++j) a_sm[i*5+j] = e[j] / s;
            }
        }
    }
}

// P2: z0 gemm (bf16 A) | bsq(B1,B1->B2) | btrans(B1)
__global__ __launch_bounds__(256) void k_p2(const ushort_t* __restrict__ featb,
        const ushort_t* __restrict__ Wh0t, ushort_t* __restrict__ zb,
        const u64* __restrict__ B1, u64* __restrict__ B2, u64* __restrict__ B1T) {
    __shared__ __align__(16) char smem[10240];
    int b = blockIdx.x, t = threadIdx.x;
    int wid = t >> 6, l = t & 63;
    if (b < 512)       role_gemm(b, t, smem, featb, nullptr, NF, Wh0t, NF, zb, nullptr);
    else if (b < 4608) role_bsq(b - 512, t, smem, B1, B1, B2);
    else               role_btrans((b - 4608)*4 + wid, wid, l, smem, B1, B1T);
}

// P3: bsq(B1,B2->B3) | btrans(B2) | ymat0
__global__ __launch_bounds__(256) void k_p3(const u64* __restrict__ B1,
        const u64* __restrict__ B2, u64* __restrict__ B3, u64* __restrict__ B2T,
        const u64* __restrict__ B1T, const u64* __restrict__ LC,
        const float* __restrict__ a_sm, ushort_t* __restrict__ y0c) {
    __shared__ __align__(16) char smem[24576];
    int b = blockIdx.x, t = threadIdx.x;
    int wid = t >> 6, l = t & 63;
    if (b < 4096)      role_bsq(b, t, smem, B1, B2, B3);
    else if (b < 5120) role_btrans((b - 4096)*4 + wid, wid, l, smem, B2, B2T);
    else               role_ymat((b - 5120)*8, t, smem, B1, B1T, LC, a_sm, y0c);
}

// P4: ygemm0 | ymat1 | bsq(B1,B3->B4)
__global__ __launch_bounds__(256) void k_p4(const ushort_t* __restrict__ y0c,
        const ushort_t* __restrict__ Wy0t, float* __restrict__ yv0,
        const u64* __restrict__ B2, const u64* __restrict__ B2T,
        const u64* __restrict__ LC, const float* __restrict__ a_sm,
        ushort_t* __restrict__ y1c,
        const u64* __restrict__ B1, const u64* __restrict__ B3, u64* __restrict__ B4) {
    __shared__ __align__(16) char smem[24576];
    int b = blockIdx.x, t = threadIdx.x;
    if (b < 512)       role_gemm(b, t, smem, y0c, nullptr, 96, Wy0t, 96, nullptr, yv0);
    else if (b < 1024) role_ymat((b - 512)*8, t, smem, B2, B2T, LC, a_sm + 5, y1c);
    else               role_bsq(b - 1024, t, smem, B1, B3, B4);
}

// P5: spmm0F (adj@z0 -> f1) | btrans(B4) | ygemm1
__global__ __launch_bounds__(256) void k_p5(const int* __restrict__ rc,
        const int* __restrict__ ci, const float* __restrict__ vl,
        const ushort_t* __restrict__ zb, const float* __restrict__ yv0,
        const float* __restrict__ b0, const int* __restrict__ lnflag,
        const float* __restrict__ a_sm, ushort_t* __restrict__ f1,
        const u64* __restrict__ B4, u64* __restrict__ B4T,
        const ushort_t* __restrict__ y1c, const ushort_t* __restrict__ Wy1t,
        float* __restrict__ yv1) {
    __shared__ __align__(16) char smem[10240];
    int b = blockIdx.x, t = threadIdx.x;
    int wid = t >> 6, l = t & 63;
    if (b < 1024)
        role_spmmF(b*4 + wid, l, rc, ci, vl, zb, yv0, b0, *lnflag, a_sm[0], f1);
    else if (b < 2048)
        role_btrans((b - 1024)*4 + wid, wid, l, smem, B4, B4T);
    else
        role_gemm(b - 2048, t, smem, y1c, nullptr, 96, Wy1t, 96, nullptr, yv1);
}

// P6: gemm z1 = f1 @ Wh1 | ymat2
__global__ __launch_bounds__(256) void k_p6(const ushort_t* __restrict__ f1,
        const ushort_t* __restrict__ Wh1t, ushort_t* __restrict__ zb,
        const u64* __restrict__ B4, const u64* __restrict__ B4T,
        const u64* __restrict__ LC, const float* __restrict__ a_sm,
        ushort_t* __restrict__ y2c) {
    __shared__ __align__(16) char smem[24576];
    int b = blockIdx.x, t = threadIdx.x;
    if (b < 512) role_gemm(b, t, smem, f1, nullptr, NH, Wh1t, NH, zb, nullptr);
    else         role_ymat((b - 512)*8, t, smem, B4, B4T, LC, a_sm + 10, y2c);
}

// P7: spmm (zb -> ub) | ygemm2
__global__ __launch_bounds__(256) void k_p7(const int* __restrict__ rc,
        const int* __restrict__ ci, const float* __restrict__ vl,
        const ushort_t* __restrict__ zb, ushort_t* __restrict__ ub,
        const ushort_t* __restrict__ y2c, const ushort_t* __restrict__ Wy2t,
        float* __restrict__ yv2) {
    __shared__ __align__(16) char smem[10240];
    int b = blockIdx.x, t = threadIdx.x;
    int wid = t >> 6, l = t & 63;
    if (b < 1024) role_spmm(b*4 + wid, l, rc, ci, vl, zb, ub);
    else          role_gemm(b - 1024, t, smem, y2c, nullptr, 96, Wy2t, 96, nullptr, yv2);
}

__global__ __launch_bounds__(256) void k_spmm(const int* __restrict__ rc,
        const int* __restrict__ ci, const float* __restrict__ vl,
        const ushort_t* __restrict__ X, ushort_t* __restrict__ Y) {
    role_spmm(blockIdx.x*4 + (threadIdx.x >> 6), threadIdx.x & 63, rc, ci, vl, X, Y);
}

__global__ __launch_bounds__(256) void k_spmmF(const int* __restrict__ rc,
        const int* __restrict__ ci, const float* __restrict__ vl,
        const ushort_t* __restrict__ X, const float* __restrict__ yv,
        const float* __restrict__ bias, const int* __restrict__ lnflag,
        const float* __restrict__ a_sm, int ai, ushort_t* __restrict__ F) {
    role_spmmF(blockIdx.x*4 + (threadIdx.x >> 6), threadIdx.x & 63, rc, ci, vl,
               X, yv, bias, *lnflag, a_sm[ai], F);
}

__global__ __launch_bounds__(256) void k_gemmz(const ushort_t* __restrict__ A,
        const ushort_t* __restrict__ Bt, ushort_t* __restrict__ C, int K) {
    __shared__ __align__(16) char smem[10240];
    role_gemm(blockIdx.x, threadIdx.x, smem, A, nullptr, K, Bt, K, C, nullptr);
}

// ================= final: [relu(featb) | relu(max(f1,f2,f3))] @ W2 + b2 -> log_softmax ===
__global__ __launch_bounds__(256) void k_final(const ushort_t* __restrict__ featb,
        const ushort_t* __restrict__ f1, const ushort_t* __restrict__ f2,
        const ushort_t* __restrict__ f3, const float* __restrict__ W2,
        const float* __restrict__ b2, float* __restrict__ out) {
    int rb = blockIdx.x * 8;
    int t = threadIdx.x;
    __shared__ float rows[8][NF + NH];
    __shared__ float part[8][8][32];
    #pragma unroll
    for (int r = 0; r < 8; ++r) {
        ushort4 v = *(const ushort4*)&featb[(size_t)(rb + r) * NF + t * 4];
        rows[r][t*4+0] = fmaxf(bf2f(v.x), 0.f);
        rows[r][t*4+1] = fmaxf(bf2f(v.y), 0.f);
        rows[r][t*4+2] = fmaxf(bf2f(v.z), 0.f);
        rows[r][t*4+3] = fmaxf(bf2f(v.w), 0.f);
    }
    #pragma unroll
    for (int q = 0; q < 2; ++q) {
        int ch = t*2 + q;
        int rr = ch >> 6, k8 = (ch & 63) * 8;
        s16x8 a = *(const s16x8*)&f1[(size_t)(rb + rr)*NH + k8];
        s16x8 bq = *(const s16x8*)&f2[(size_t)(rb + rr)*NH + k8];
        s16x8 cq = *(const s16x8*)&f3[(size_t)(rb + rr)*NH + k8];
        #pragma unroll
        for (int j = 0; j < 8; ++j) {
            float m = fmaxf(fmaxf(bf2f((ushort_t)a[j]), bf2f((ushort_t)bq[j])),
                            bf2f((ushort_t)cq[j]));
            rows[rr][NF + k8 + j] = fmaxf(m, 0.f);
        }
    }
    __syncthreads();
    int c = t & 31, g = t >> 5;
    float acc[8] = {0,0,0,0,0,0,0,0};
    for (int k = g * 192; k < (g + 1) * 192; ++k) {
        float w = W2[(size_t)k * NC + c];
        #pragma unroll
        for (int r = 0; r < 8; ++r) acc[r] += rows[r][k] * w;
    }
    #pragma unroll
    for (int r = 0; r < 8; ++r) part[g][r][c] = acc[r];
    __syncthreads();
    int r = g;
    float lg = b2[c];
    #pragma unroll
    for (int gg = 0; gg < 8; ++gg) lg += part[gg][r][c];
    float m = lg;
    #pragma unroll
    for (int o = 16; o > 0; o >>= 1) m = fmaxf(m, __shfl_xor(m, o, 32));
    float e = expf(lg - m), s = e;
    #pragma unroll
    for (int o = 16; o > 0; o >>= 1) s += __shfl_xor(s, o, 32);
    out[(size_t)(rb + r) * NC + c] = lg - m - logf(s);
}

extern "C" void kernel_launch(void* const* d_in, const int* in_sizes, int n_in,
                              void* d_out, int out_size, void* d_ws, size_t ws_size,
                              hipStream_t stream) {
    const float* adj      = (const float*)d_in[0];
    const float* features = (const float*)d_in[1];
    const float* y        = (const float*)d_in[2];
    const float* W0       = (const float*)d_in[3];
    const float* b0       = (const float*)d_in[4];
    const float* W1_0     = (const float*)d_in[5];
    const float* b1_0     = (const float*)d_in[6];
    const float* W1_1     = (const float*)d_in[7];
    const float* b1_1     = (const float*)d_in[8];
    const float* W2       = (const float*)d_in[9];
    const float* b2       = (const float*)d_in[10];
    const float* alphas   = (const float*)d_in[11];
    const int*   lnflag   = (const int*)d_in[12];
    float* out = (float*)d_out;

    char* ws = (char*)d_ws;
    size_t off = 0;
    auto alloc = [&](size_t bytes) -> char* {
        char* p = ws + off;
        off = (off + bytes + 255) & ~(size_t)255;
        return p;
    };
    float* a_sm   = (float*)alloc(16 * 4);
    int*   rowcnt = (int*)alloc((size_t)NN * 4);
    int*   colidx = (int*)alloc((size_t)NN * 64 * 4);
    float* vals   = (float*)alloc((size_t)NN * 64 * 4);
    u64* B1  = (u64*)alloc((size_t)NN * 64 * 8);
    u64* B2  = (u64*)alloc((size_t)NN * 64 * 8);
    u64* B3  = (u64*)alloc((size_t)NN * 64 * 8);
    u64* B4  = (u64*)alloc((size_t)NN * 64 * 8);
    u64* B1T = (u64*)alloc((size_t)NN * 64 * 8);
    u64* B2T = (u64*)alloc((size_t)NN * 64 * 8);
    u64* B4T = (u64*)alloc((size_t)NN * 64 * 8);
    u64* LC  = (u64*)alloc((size_t)NC * 64 * 8);
    ushort_t* featb = (ushort_t*)alloc((size_t)NN * NF * 2);
    ushort_t* Wh0t = (ushort_t*)alloc((size_t)NH * NF * 2);
    ushort_t* Wh1t = (ushort_t*)alloc((size_t)NH * NH * 2);
    ushort_t* Wh2t = (ushort_t*)alloc((size_t)NH * NH * 2);
    ushort_t* Wy0t = (ushort_t*)alloc((size_t)NH * 96 * 2);
    ushort_t* Wy1t = (ushort_t*)alloc((size_t)NH * 96 * 2);
    ushort_t* Wy2t = (ushort_t*)alloc((size_t)NH * 96 * 2);
    ushort_t* y0c  = (ushort_t*)alloc((size_t)NN * 96 * 2);
    ushort_t* y1c  = (ushort_t*)alloc((size_t)NN * 96 * 2);
    ushort_t* y2c  = (ushort_t*)alloc((size_t)NN * 96 * 2);
    float* yv0 = (float*)alloc((size_t)NN * NH * 4);
    float* yv1 = (float*)alloc((size_t)NN * NH * 4);
    float* yv2 = (float*)alloc((size_t)NN * NH * 4);
    ushort_t* zb = (ushort_t*)alloc((size_t)NN * NH * 2);
    ushort_t* ub = (ushort_t*)alloc((size_t)NN * NH * 2);
    ushort_t* vb = (ushort_t*)alloc((size_t)NN * NH * 2);
    ushort_t* f1 = (ushort_t*)alloc((size_t)NN * NH * 2);
    ushort_t* f2 = (ushort_t*)alloc((size_t)NN * NH * 2);
    ushort_t* f3 = (ushort_t*)alloc((size_t)NN * NH * 2);

    // P1: build | featbf | LC | W transposes | alphas
    k_setup<<<6305, 256, 0, stream>>>(adj, features, featb, y, LC, W0, W1_0, W1_1,
                                      Wh0t, Wy0t, Wh1t, Wy1t, Wh2t, Wy2t,
                                      alphas, a_sm, B1, rowcnt, colidx, vals);
    // P2: z0 gemm (bf16) | bsq B2 | btrans B1
    k_p2<<<5632, 256, 0, stream>>>(featb, Wh0t, zb, B1, B2, B1T);
    // P3: bsq B3 | btrans B2 | ymat0
    k_p3<<<5632, 256, 0, stream>>>(B1, B2, B3, B2T, B1T, LC, a_sm, y0c);
    // P4: ygemm0 | ymat1 | bsq B4
    k_p4<<<5120, 256, 0, stream>>>(y0c, Wy0t, yv0, B2, B2T, LC, a_sm, y1c, B1, B3, B4);
    // P5: spmm0F -> f1 | btrans B4 | ygemm1
    k_p5<<<2560, 256, 0, stream>>>(rowcnt, colidx, vals, zb, yv0, b0, lnflag, a_sm,
                                   f1, B4, B4T, y1c, Wy1t, yv1);
    // P6: z1 gemm | ymat2
    k_p6<<<1024, 256, 0, stream>>>(f1, Wh1t, zb, B4, B4T, LC, a_sm, y2c);
    // P7: spmm z1 -> ub | ygemm2
    k_p7<<<1536, 256, 0, stream>>>(rowcnt, colidx, vals, zb, ub, y2c, Wy2t, yv2);
    // P8: spmm1F -> f2
    k_spmmF<<<1024, 256, 0, stream>>>(rowcnt, colidx, vals, ub, yv1, b1_0, lnflag,
                                      a_sm, 5, f2);
    // P9: z2 gemm
    k_gemmz<<<512, 256, 0, stream>>>(f2, Wh2t, zb, NH);
    // P10-12: spmm chain
    k_spmm<<<1024, 256, 0, stream>>>(rowcnt, colidx, vals, zb, ub);
    k_spmm<<<1024, 256, 0, stream>>>(rowcnt, colidx, vals, ub, vb);
    k_spmm<<<1024, 256, 0, stream>>>(rowcnt, colidx, vals, vb, ub);
    // P13: spmm2F -> f3
    k_spmmF<<<1024, 256, 0, stream>>>(rowcnt, colidx, vals, ub, yv2, b1_1, lnflag,
                                      a_sm, 10, f3);
    // P14: final
    k_final<<<512, 256, 0, stream>>>(featb, f1, f2, f3, W2, b2, out);
}